// Round 5
// baseline (1109.771 us; speedup 1.0000x reference)
//
#include <hip/hip_runtime.h>

// ChainMessagePassing: out[n] = sum over edges with dst==n of x[src], over two edge lists.
// x: [N=100000, 64] fp32; indices: [2, E=3200000] (src row 0, dst row 1), int64 or int32.
//
// R8: per-XCD dst-partitioned scatter + tile-major CSR + predicated concat-stream gather.
//  - R7 post-mortem: scatter WRITE_SIZE 407MB = 64B HBM line per 4B random store.
//    Same as R5 (nt irrelevant). Cause: all 8 XCDs scatter into one 25.6MB region ->
//    per-L2 write footprint >4MB (evict before line assembly) + cross-XCD partial lines.
//  - Fix: read XCC_ID (s_getreg, HW-verified), partition dst into 8 ranges; XCD g
//    streams ALL indices (nt) but scatters only dst in range g -> write set 3.2MB+cursors,
//    L2-resident, lines fully assembled. Chunk queues with stealing => correct even if
//    XCD mapping assumption fails (only slower).
//  - Gather: keys tile-major (tile*N+dst): per tile, a team's 4 nodes are ONE contiguous
//    srcbuf stream (avg ~20 edges, was 4.9-edge runs). 4-deep batches, per-edge node
//    assignment by boundary predication into 4 named accs. srcbuf reads cached (no nt).
//    Temporal tile sweep keeps chip-wide x working set ~1 tile (2MB, L2-resident).

static constexpr int D = 64;
static constexpr int Q = 16;           // float4 quads per row
static constexpr int SB = 256;         // scan blocks (== scan block dim)
static constexpr int NXCD = 8;
static constexpr int SCHUNK = 16384;   // edges per scatter chunk

typedef float v4f __attribute__((ext_vector_type(4)));

// ---- index dtype sniffer: int64 nonneg <2^31 has all-zero odd dwords ----
__global__ void detect_idx_dtype(const int* __restrict__ w, int* __restrict__ flag) {
    int tid = threadIdx.x;  // one wave
    int v = w[2 * tid + 1];
    unsigned long long m = __ballot(v != 0);
    if (tid == 0) *flag = (m == 0ULL) ? 1 : 0;
}

__device__ __forceinline__ int load_idx_nt(const void* idx, long long i, int is64) {
    return is64 ? (int)__builtin_nontemporal_load(((const long long*)idx) + i)
                : __builtin_nontemporal_load(((const int*)idx) + i);
}

__device__ __forceinline__ int get_xcd() {
    unsigned id;
    asm volatile("s_getreg_b32 %0, hwreg(HW_REG_XCC_ID)" : "=s"(id));
    return (int)(id & (NXCD - 1));
}

// ---- phase 1: histogram over tile-major (tile,dst) keys ----
__global__ __launch_bounds__(256) void hist_kernel(
        const void* __restrict__ up, const void* __restrict__ down,
        int* __restrict__ keys, const int* __restrict__ flag, int E,
        int shift, int N) {
    const int is64 = *flag;
    const long long total = 2LL * E;
    const long long ng = (total + 7) >> 3;
    const long long stride = (long long)gridDim.x * blockDim.x;
    for (long long t = (long long)blockIdx.x * blockDim.x + threadIdx.x;
         t < ng; t += stride) {
        const long long e0 = t << 3;
        #pragma unroll
        for (int k = 0; k < 8; k++) {
            long long e = e0 + k;
            if (e < total) {
                const void* idx = up; long long ee = e;
                if (ee >= E) { idx = down; ee -= E; }
                int src = load_idx_nt(idx, ee, is64);
                int dst = load_idx_nt(idx, E + ee, is64);
                atomicAdd(&keys[(long long)(src >> shift) * N + dst], 1);
            }
        }
    }
}

// ---- phase 2a: per-block partial sums ----
__global__ __launch_bounds__(256) void scan_partials_kernel(
        const int* __restrict__ keys, int* __restrict__ partials,
        long long bins, int cpt) {
    __shared__ int red[256];
    const int blk = blockIdx.x, tid = threadIdx.x;
    const long long base = (long long)(blk * 256 + tid) * cpt;
    int s = 0;
    for (int k = 0; k < cpt; k++) {
        long long i = base + k;
        if (i < bins) s += keys[i];
    }
    red[tid] = s;
    __syncthreads();
    for (int off = 128; off > 0; off >>= 1) {
        if (tid < off) red[tid] += red[tid + off];
        __syncthreads();
    }
    if (tid == 0) partials[blk] = red[0];
}

// ---- phase 2b: in-place exclusive scan (keys: counts -> exclusive offsets) ----
__global__ __launch_bounds__(256) void scan_apply_kernel(
        int* __restrict__ keys, const int* __restrict__ partials,
        long long bins, int cpt) {
    __shared__ int sh[256];
    const int blk = blockIdx.x, tid = threadIdx.x;
    sh[tid] = (tid < blk) ? partials[tid] : 0;   // SB == 256 == blockDim
    __syncthreads();
    for (int off = 128; off > 0; off >>= 1) {
        if (tid < off) sh[tid] += sh[tid + off];
        __syncthreads();
    }
    const int bbase = sh[0];
    __syncthreads();
    const long long base = (long long)(blk * 256 + tid) * cpt;
    int s = 0;
    for (int k = 0; k < cpt; k++) {
        long long i = base + k;
        if (i < bins) s += keys[i];
    }
    sh[tid] = s;
    __syncthreads();
    for (int off = 1; off < 256; off <<= 1) {
        int t = (tid >= off) ? sh[tid - off] : 0;
        __syncthreads();
        sh[tid] += t;
        __syncthreads();
    }
    int run = bbase + ((tid == 0) ? 0 : sh[tid - 1]);
    for (int k = 0; k < cpt; k++) {
        long long i = base + k;
        if (i < bins) {
            int c = keys[i];
            keys[i] = run;      // in-place: exclusive offset
            run += c;
        }
    }
}

// ---- phase 3: per-XCD dst-partitioned scatter; keys become inclusive ends ----
// Each XCD streams the full index list (nt, no allocate) and scatters only its
// dst-range: write set = 3.2MB srcbuf region + ~650KB cursors, L2-resident.
// Chunk queues + stealing => correct regardless of block->XCD placement.
__global__ __launch_bounds__(256) void scatter_kernel(
        const void* __restrict__ up, const void* __restrict__ down,
        int* __restrict__ keys, int* __restrict__ srcbuf,
        int* __restrict__ queues, const int* __restrict__ flag,
        int E, int shift, int N, int rangesz, int nchunks) {
    __shared__ int sc;
    const int is64 = *flag;
    const long long total = 2LL * E;
    const int my = get_xcd();
    for (int gi = 0; gi < NXCD; gi++) {
        const int g = (my + gi) & (NXCD - 1);
        const int lo = g * rangesz;
        const int hi = lo + rangesz;
        for (;;) {
            __syncthreads();
            if (threadIdx.x == 0) sc = atomicAdd(&queues[g], 1);
            __syncthreads();
            const int c = sc;
            if (c >= nchunks) break;
            const long long cs = (long long)c * SCHUNK;
            const long long ce = min(total, cs + (long long)SCHUNK);
            for (long long e = cs + threadIdx.x; e < ce; e += 256) {
                const void* idx = up; long long ee = e;
                if (ee >= E) { idx = down; ee -= E; }
                const int dst = load_idx_nt(idx, E + ee, is64);
                if (dst >= lo && dst < hi) {
                    const int src = load_idx_nt(idx, ee, is64);
                    const int pos =
                        atomicAdd(&keys[(long long)(src >> shift) * N + dst], 1);
                    srcbuf[pos] = src;
                }
            }
        }
    }
}

// ---- phase 4: temporal tile-swept gather, concat-4 streams, predicated accs ----
__global__ __launch_bounds__(256) void gather_kernel(
        const float* __restrict__ x, const int* __restrict__ keys,
        const int* __restrict__ srcs, float* __restrict__ out,
        int N, int NT) {
    const int tid = threadIdx.x;
    const int team = tid >> 4;        // 0..15
    const int q = tid & 15;           // float4 quad within row
    const int bn = blockIdx.x * 64 + team * 4;
    const float* xq = x + q * 4;

    float4 acc0 = make_float4(0.f, 0.f, 0.f, 0.f);
    float4 acc1 = acc0, acc2 = acc0, acc3 = acc0;

#define ADDP(v, p) do {                                                        \
        const bool c1 = (p) < b1, c2 = (p) < b2, c3 = (p) < b3;                \
        acc0.x += c1 ? (v).x : 0.f; acc0.y += c1 ? (v).y : 0.f;                \
        acc0.z += c1 ? (v).z : 0.f; acc0.w += c1 ? (v).w : 0.f;                \
        const bool d1 = !c1 && c2;                                             \
        acc1.x += d1 ? (v).x : 0.f; acc1.y += d1 ? (v).y : 0.f;                \
        acc1.z += d1 ? (v).z : 0.f; acc1.w += d1 ? (v).w : 0.f;                \
        const bool d2 = !c2 && c3;                                             \
        acc2.x += d2 ? (v).x : 0.f; acc2.y += d2 ? (v).y : 0.f;                \
        acc2.z += d2 ? (v).z : 0.f; acc2.w += d2 ? (v).w : 0.f;                \
        const bool d3 = !c3;                                                   \
        acc3.x += d3 ? (v).x : 0.f; acc3.y += d3 ? (v).y : 0.f;                \
        acc3.z += d3 ? (v).z : 0.f; acc3.w += d3 ? (v).w : 0.f;                \
    } while (0)

    for (int t = 0; t < NT; t++) {
        if (bn < N) {
            const long long tN = (long long)t * N;
            const int b0 = (tN + bn == 0) ? 0 : keys[tN + bn - 1];
            const int b1 = keys[tN + bn];
            const int b2 = keys[tN + min(bn + 1, N - 1)];
            const int b3 = keys[tN + min(bn + 2, N - 1)];
            const int b4 = keys[tN + min(bn + 3, N - 1)];
            int e = b0;
            for (; e + 4 <= b4; e += 4) {
                const int s0 = srcs[e + 0];
                const int s1 = srcs[e + 1];
                const int s2 = srcs[e + 2];
                const int s3 = srcs[e + 3];
                const float4 v0 = *(const float4*)(xq + (long long)s0 * D);
                const float4 v1 = *(const float4*)(xq + (long long)s1 * D);
                const float4 v2 = *(const float4*)(xq + (long long)s2 * D);
                const float4 v3 = *(const float4*)(xq + (long long)s3 * D);
                ADDP(v0, e + 0);
                ADDP(v1, e + 1);
                ADDP(v2, e + 2);
                ADDP(v3, e + 3);
            }
            for (; e < b4; e++) {
                const int s = srcs[e];
                const float4 v = *(const float4*)(xq + (long long)s * D);
                ADDP(v, e);
            }
        }
        __syncthreads();   // keep block's teams on the same tile epoch
    }
#undef ADDP

    if (bn < N) {
        v4f a = { acc0.x, acc0.y, acc0.z, acc0.w };
        __builtin_nontemporal_store(a, (v4f*)(out + (long long)bn * D + q * 4));
    }
    if (bn + 1 < N) {
        v4f a = { acc1.x, acc1.y, acc1.z, acc1.w };
        __builtin_nontemporal_store(a, (v4f*)(out + (long long)(bn + 1) * D + q * 4));
    }
    if (bn + 2 < N) {
        v4f a = { acc2.x, acc2.y, acc2.z, acc2.w };
        __builtin_nontemporal_store(a, (v4f*)(out + (long long)(bn + 2) * D + q * 4));
    }
    if (bn + 3 < N) {
        v4f a = { acc3.x, acc3.y, acc3.z, acc3.w };
        __builtin_nontemporal_store(a, (v4f*)(out + (long long)(bn + 3) * D + q * 4));
    }
}

// ---- fallback: direct fp32 atomics (R1), needs no workspace ----
__global__ __launch_bounds__(256) void scatter_add_kernel(
        const float* __restrict__ x, const void* __restrict__ up_idx,
        const void* __restrict__ down_idx, float* __restrict__ out,
        const int* __restrict__ dtype_flag, int num_edges) {
    const int is64 = *dtype_flag;
    const long long total = 2LL * num_edges * Q;
    const long long stride = (long long)gridDim.x * blockDim.x;
    for (long long t = (long long)blockIdx.x * blockDim.x + threadIdx.x;
         t < total; t += stride) {
        const int quad = (int)(t & (Q - 1));
        long long eg = t >> 4;
        const void* idx = up_idx;
        if (eg >= num_edges) { idx = down_idx; eg -= num_edges; }
        int src = load_idx_nt(idx, eg, is64);
        int dst = load_idx_nt(idx, num_edges + eg, is64);
        const float4 v = *(const float4*)(x + (long long)src * D + quad * 4);
        float* o = out + (long long)dst * D + quad * 4;
        unsafeAtomicAdd(o + 0, v.x);
        unsafeAtomicAdd(o + 1, v.y);
        unsafeAtomicAdd(o + 2, v.z);
        unsafeAtomicAdd(o + 3, v.w);
    }
}

extern "C" void kernel_launch(void* const* d_in, const int* in_sizes, int n_in,
                              void* d_out, int out_size, void* d_ws, size_t ws_size,
                              hipStream_t stream) {
    const float* x = (const float*)d_in[0];
    const void* up_idx = d_in[1];
    const void* down_idx = d_in[2];
    float* out = (float*)d_out;

    const int E = in_sizes[1] / 2;   // [2, E]
    const int N = out_size / D;      // [N, 64]
    const long long Etot = 2LL * E;

    // tile shift: 8192 rows (2MB) preferred; coarsen if ws is tight
    int shift = 13;
    long long bins = 0;
    size_t ws_need = (size_t)-1;
    while (true) {
        int nt = (int)(((long long)(N - 1) >> shift) + 1);
        bins = (long long)N * nt;
        ws_need = ((size_t)64 + 64 + (size_t)bins + 320 + (size_t)Etot) * 4 + 64;
        if ((ws_need <= ws_size && bins < (1LL << 31)) || shift >= 24) break;
        shift++;
    }
    const int NT = (int)(((long long)(N - 1) >> shift) + 1);

    // ws layout (ints): flag(64) | queues(64) | keys[bins] | partials[320] | srcbuf[Etot]
    int* ws_i = (int*)d_ws;
    int* flag = ws_i;
    int* queues = ws_i + 64;
    int* keys = queues + 64;
    int* partials = keys + bins;
    int* srcbuf = partials + 320;

    detect_idx_dtype<<<1, 64, 0, stream>>>((const int*)up_idx, flag);

    if (ws_size >= ws_need && Etot < (1LL << 31) && bins < (1LL << 31) && N >= 1) {
        hipMemsetAsync(queues, 0, (size_t)(64 + bins) * sizeof(int), stream);
        hist_kernel<<<2048, 256, 0, stream>>>(up_idx, down_idx, keys, flag, E, shift, N);
        const int cpt = (int)((bins + SB * 256 - 1) / (SB * 256));
        scan_partials_kernel<<<SB, 256, 0, stream>>>(keys, partials, bins, cpt);
        scan_apply_kernel<<<SB, 256, 0, stream>>>(keys, partials, bins, cpt);
        const int rangesz = (N + NXCD - 1) / NXCD;
        const int nchunks = (int)((Etot + SCHUNK - 1) / SCHUNK);
        scatter_kernel<<<2048, 256, 0, stream>>>(up_idx, down_idx, keys, srcbuf,
                                                 queues, flag, E, shift, N,
                                                 rangesz, nchunks);
        gather_kernel<<<(N + 63) / 64, 256, 0, stream>>>(x, keys, srcbuf, out, N, NT);
    } else {
        hipMemsetAsync(d_out, 0, (size_t)out_size * sizeof(float), stream);
        scatter_add_kernel<<<8192, 256, 0, stream>>>(x, up_idx, down_idx, out, flag, E);
    }
}

// Round 6
// 528.382 us; speedup vs baseline: 2.1003x; 2.1003x over previous
//
#include <hip/hip_runtime.h>

// ChainMessagePassing: out[n] = sum over edges with dst==n of x[src], over two edge lists.
// x: [N=100000, 64] fp32; indices: [2, E=3200000] (src row 0, dst row 1), int64 or int32.
//
// R9: R4's proven pipeline (best measured: 496us total, gather 215us) with ONE
// structural change, confined to the gather: the per-bucket LDS counting sort key
// widens from dstlo (64 bins) to (src>>13)*64+dstlo (NT*64 bins), and the
// accumulate loop sweeps src-tiles in order with persistent register accumulators.
// Rationale: R4 gather was L2-miss-BW-bound (FETCH 686MB at the ~3.4TB/s L2-fill
// plateau = its 215us). x (25.6MB) doesn't fit a 4MB per-XCD L2 -> ~3.3x refetch.
// All gather blocks sweep tiles in the same order with near-equal work, so the
// chip-wide x working set at any instant is ~1-2 tiles (2-4MB, L2-resident):
// expected x fill ~8x25.6=205MB, FETCH ~260-300MB, gather ~100-130us.
// Prep is R4 verbatim (LDS-aggregated scatter: contiguous per-bucket sub-runs,
// no fine-grained global scatter - R5/R7/R8 proved 4B cursor-scatter costs
// 64B HBM/line: WRITE_SIZE 391/407/472MB) + nt index loads (don't evict write
// lines from L2) + CHUNK 8192 (782 blocks = 3/CU, was 1.5/CU).

static constexpr int D = 64;
static constexpr int Q = 16;          // float4 quads per row
static constexpr int NPB = 64;        // nodes per bucket
static constexpr int NPB_SHIFT = 6;
static constexpr int CHUNK = 8192;    // edges per scatter block
static constexpr int CH = 4096;       // edges per gather sort chunk (16 KB LDS)
static constexpr int MAXT = 32;       // max src tiles (nbins <= 2048)

// ---- index dtype sniffer: int64 nonneg <2^31 has all-zero odd dwords ----
__global__ void detect_idx_dtype(const int* __restrict__ w, int* __restrict__ flag) {
    int tid = threadIdx.x;  // one wave
    int v = w[2 * tid + 1];
    unsigned long long m = __ballot(v != 0);
    if (tid == 0) *flag = (m == 0ULL) ? 1 : 0;
}

__device__ __forceinline__ int load_idx_nt(const void* idx, long long i, int is64) {
    return is64 ? (int)__builtin_nontemporal_load(((const long long*)idx) + i)
                : __builtin_nontemporal_load(((const int*)idx) + i);
}

// ---- phase 1: bucket histogram, LDS-aggregated ----
__global__ __launch_bounds__(256) void bucket_hist_kernel(
        const void* __restrict__ up, const void* __restrict__ down,
        int* __restrict__ bcounts, const int* __restrict__ flag, int E, int NB) {
    extern __shared__ int lcnt[];
    const int is64 = *flag;
    for (int i = threadIdx.x; i < NB; i += blockDim.x) lcnt[i] = 0;
    __syncthreads();
    const long long total = 2LL * E;
    const long long stride = (long long)gridDim.x * blockDim.x;
    for (long long e = (long long)blockIdx.x * blockDim.x + threadIdx.x;
         e < total; e += stride) {
        const void* idx = up; long long ee = e;
        if (ee >= E) { idx = down; ee -= E; }
        int dst = load_idx_nt(idx, E + ee, is64);
        atomicAdd(&lcnt[dst >> NPB_SHIFT], 1);
    }
    __syncthreads();
    for (int i = threadIdx.x; i < NB; i += blockDim.x)
        if (lcnt[i]) atomicAdd(&bcounts[i], lcnt[i]);
}

// ---- phase 2: exclusive scan over NB buckets, one block ----
__global__ __launch_bounds__(1024) void scan_kernel(
        const int* __restrict__ counts, int* __restrict__ offsets,
        int* __restrict__ cursors, int NB) {
    __shared__ int sums[1024];
    const int tid = threadIdx.x;
    const int chunk = (NB + 1023) / 1024;
    const int start = tid * chunk;
    const int end = min(start + chunk, NB);
    int s = 0;
    for (int i = start; i < end; i++) s += counts[i];
    sums[tid] = s;
    __syncthreads();
    for (int off = 1; off < 1024; off <<= 1) {
        int t = (tid >= off) ? sums[tid - off] : 0;
        __syncthreads();
        sums[tid] += t;
        __syncthreads();
    }
    int run = (tid == 0) ? 0 : sums[tid - 1];
    for (int i = start; i < end; i++) {
        offsets[i] = run;
        cursors[i] = run;
        run += counts[i];
    }
    if (tid == 1023) offsets[NB] = run;
}

// ---- phase 3: scatter packed (src<<6 | dst&63) into bucket bins ----
// LDS-aggregated: per-chunk counts -> one atomicAdd per (block,bucket) reserves
// a contiguous sub-run (~5-10 sequential 4B writes per 64B line).
__global__ __launch_bounds__(256) void bucket_scatter_kernel(
        const void* __restrict__ up, const void* __restrict__ down,
        int* __restrict__ gcursor, unsigned* __restrict__ packed,
        const int* __restrict__ flag, int E, int NB) {
    extern __shared__ int lds[];
    int* cnt = lds;        // [NB]
    int* base = lds + NB;  // [NB]
    const int is64 = *flag;
    const long long total = 2LL * E;
    const long long cs = (long long)blockIdx.x * CHUNK;
    if (cs >= total) return;
    const long long ce = min(total, cs + (long long)CHUNK);

    for (int i = threadIdx.x; i < NB; i += blockDim.x) cnt[i] = 0;
    __syncthreads();
    for (long long e = cs + threadIdx.x; e < ce; e += blockDim.x) {
        const void* idx = up; long long ee = e;
        if (ee >= E) { idx = down; ee -= E; }
        int dst = load_idx_nt(idx, E + ee, is64);
        atomicAdd(&cnt[dst >> NPB_SHIFT], 1);
    }
    __syncthreads();
    for (int i = threadIdx.x; i < NB; i += blockDim.x) {
        int c = cnt[i];
        base[i] = c ? atomicAdd(&gcursor[i], c) : 0;
        cnt[i] = 0;  // reuse as local cursor
    }
    __syncthreads();
    for (long long e = cs + threadIdx.x; e < ce; e += blockDim.x) {
        const void* idx = up; long long ee = e;
        if (ee >= E) { idx = down; ee -= E; }
        int src = load_idx_nt(idx, ee, is64);
        int dst = load_idx_nt(idx, E + ee, is64);
        int b = dst >> NPB_SHIFT;
        int pos = base[b] + atomicAdd(&cnt[b], 1);
        packed[pos] = ((unsigned)src << NPB_SHIFT) | (unsigned)(dst & (NPB - 1));
    }
}

// ---- phase 4: per-bucket counting sort by (src-tile, dstlo) + tile-swept
// register gather. Group g (16 lanes) owns local nodes 4g..4g+3; accumulates
// float4 quads in VGPRs across ALL tiles (persistent acc), so the x working
// set at any instant is ~1 tile chip-wide (2MB, L2-resident per XCD). ----
__global__ __launch_bounds__(256) void bucket_gather_kernel(
        const float* __restrict__ x, const int* __restrict__ offsets,
        const unsigned* __restrict__ packed, float* __restrict__ out,
        int N, int shift, int NT) {
    extern __shared__ int lds[];
    unsigned* sorted = (unsigned*)lds;        // [CH]
    int* cnt = lds + CH;                      // [nbins]
    int* cursor = cnt + NT * NPB;             // [nbins]
    int* binoff = cursor + NT * NPB;          // [nbins+1]
    const int nbins = NT * NPB;

    const int b = blockIdx.x;
    const int tid = threadIdx.x;
    const int g = tid >> 4;   // group 0..15
    const int q = tid & 15;   // quad within row
    const int beg = offsets[b], end = offsets[b + 1];
    const float* xq = x + q * 4;

    float4 acc[4];
    acc[0] = acc[1] = acc[2] = acc[3] = make_float4(0.f, 0.f, 0.f, 0.f);

    for (int cs = beg; cs < end; cs += CH) {
        const int m = min(CH, end - cs);
        for (int i = tid; i < nbins; i += 256) cnt[i] = 0;
        __syncthreads();
        for (int i = tid; i < m; i += 256) {
            unsigned p = __builtin_nontemporal_load(packed + cs + i);
            int key = (int)((p >> (NPB_SHIFT + shift)) << NPB_SHIFT) | (int)(p & (NPB - 1));
            atomicAdd(&cnt[key], 1);
        }
        __syncthreads();
        if (tid < 64) {  // wave 0: scan over nbins (K bins per lane)
            const int K = (nbins + 63) >> 6;
            const int base = tid * K;
            int S = 0;
            for (int k = 0; k < K; k++) {
                int i = base + k;
                if (i < nbins) S += cnt[i];
            }
            int inc = S;
            #pragma unroll
            for (int off = 1; off < 64; off <<= 1) {
                int t = __shfl_up(inc, off, 64);
                if (tid >= off) inc += t;
            }
            int run = inc - S;  // exclusive lane offset
            for (int k = 0; k < K; k++) {
                int i = base + k;
                if (i < nbins) {
                    int c = cnt[i];
                    cursor[i] = run;
                    binoff[i + 1] = run + c;
                    run += c;
                }
            }
            if (tid == 0) binoff[0] = 0;
        }
        __syncthreads();
        for (int i = tid; i < m; i += 256) {
            unsigned p = __builtin_nontemporal_load(packed + cs + i);
            int key = (int)((p >> (NPB_SHIFT + shift)) << NPB_SHIFT) | (int)(p & (NPB - 1));
            int pos = atomicAdd(&cursor[key], 1);
            sorted[pos] = p;
        }
        __syncthreads();
        // tile-swept accumulation: outer loop over src tiles
        for (int t = 0; t < NT; t++) {
            #pragma unroll
            for (int j = 0; j < 4; j++) {
                const int dl = 4 * g + j;
                const int key = t * NPB + dl;
                const int rb = binoff[key], re = binoff[key + 1];
                int e = rb;
                for (; e + 3 < re; e += 4) {  // 4 row-gathers in flight
                    unsigned p0 = sorted[e], p1 = sorted[e + 1];
                    unsigned p2 = sorted[e + 2], p3 = sorted[e + 3];
                    const float4 v0 = *(const float4*)(xq + ((long long)(p0 >> NPB_SHIFT)) * D);
                    const float4 v1 = *(const float4*)(xq + ((long long)(p1 >> NPB_SHIFT)) * D);
                    const float4 v2 = *(const float4*)(xq + ((long long)(p2 >> NPB_SHIFT)) * D);
                    const float4 v3 = *(const float4*)(xq + ((long long)(p3 >> NPB_SHIFT)) * D);
                    acc[j].x += (v0.x + v1.x) + (v2.x + v3.x);
                    acc[j].y += (v0.y + v1.y) + (v2.y + v3.y);
                    acc[j].z += (v0.z + v1.z) + (v2.z + v3.z);
                    acc[j].w += (v0.w + v1.w) + (v2.w + v3.w);
                }
                for (; e < re; e++) {
                    unsigned p = sorted[e];
                    const float4 v = *(const float4*)(xq + ((long long)(p >> NPB_SHIFT)) * D);
                    acc[j].x += v.x; acc[j].y += v.y; acc[j].z += v.z; acc[j].w += v.w;
                }
            }
        }
        __syncthreads();  // gather reads done before next chunk reuses LDS
    }

    const int node0 = b * NPB;
    #pragma unroll
    for (int j = 0; j < 4; j++) {
        const int node = node0 + 4 * g + j;
        if (node < N)
            *(float4*)(out + (long long)node * D + q * 4) = acc[j];
    }
}

// ---- fallback: direct fp32 atomics (R1), needs no workspace ----
__global__ __launch_bounds__(256) void scatter_add_kernel(
        const float* __restrict__ x, const void* __restrict__ up_idx,
        const void* __restrict__ down_idx, float* __restrict__ out,
        const int* __restrict__ dtype_flag, int num_edges) {
    const int is64 = *dtype_flag;
    const long long total = 2LL * num_edges * Q;
    const long long stride = (long long)gridDim.x * blockDim.x;
    for (long long t = (long long)blockIdx.x * blockDim.x + threadIdx.x;
         t < total; t += stride) {
        const int quad = (int)(t & (Q - 1));
        long long eg = t >> 4;
        const void* idx = up_idx;
        if (eg >= num_edges) { idx = down_idx; eg -= num_edges; }
        int src = load_idx_nt(idx, eg, is64);
        int dst = load_idx_nt(idx, num_edges + eg, is64);
        const float4 v = *(const float4*)(x + (long long)src * D + quad * 4);
        float* o = out + (long long)dst * D + quad * 4;
        unsafeAtomicAdd(o + 0, v.x);
        unsafeAtomicAdd(o + 1, v.y);
        unsafeAtomicAdd(o + 2, v.z);
        unsafeAtomicAdd(o + 3, v.w);
    }
}

extern "C" void kernel_launch(void* const* d_in, const int* in_sizes, int n_in,
                              void* d_out, int out_size, void* d_ws, size_t ws_size,
                              hipStream_t stream) {
    const float* x = (const float*)d_in[0];
    const void* up_idx = d_in[1];
    const void* down_idx = d_in[2];
    float* out = (float*)d_out;

    const int E = in_sizes[1] / 2;   // [2, E]
    const int N = out_size / D;      // [N, 64]
    const int NB = (N + NPB - 1) / NPB;
    const long long Etot = 2LL * E;

    // src tile shift: 8192 rows (2MB) preferred; coarsen so NT <= MAXT
    int shift = 13;
    while ((((long long)(N - 1) >> shift) + 1) > MAXT) shift++;
    const int NT = (int)(((long long)(N - 1) >> shift) + 1);

    // ws layout (ints): flag(64) | counts[NB] | offsets[NB+1] pad | cursors[NB] | packed[2E]
    int* ws_i = (int*)d_ws;
    int* flag = ws_i;
    int* counts = ws_i + 64;
    int* offsets = counts + NB;
    int* cursors = offsets + NB + 15;
    unsigned* packed = (unsigned*)(cursors + NB);
    const size_t ws_need = (size_t)(64 + 3LL * NB + 16 + Etot) * 4 + 64;

    detect_idx_dtype<<<1, 64, 0, stream>>>((const int*)up_idx, flag);

    if (ws_size >= ws_need && N <= (1 << 25) && Etot < (1LL << 31)) {
        hipMemsetAsync(counts, 0, (size_t)NB * sizeof(int), stream);
        bucket_hist_kernel<<<1024, 256, NB * sizeof(int), stream>>>(
            up_idx, down_idx, counts, flag, E, NB);
        scan_kernel<<<1, 1024, 0, stream>>>(counts, offsets, cursors, NB);
        const int sblocks = (int)((Etot + CHUNK - 1) / CHUNK);
        bucket_scatter_kernel<<<sblocks, 256, 2 * NB * sizeof(int), stream>>>(
            up_idx, down_idx, cursors, packed, flag, E, NB);
        const int nbins = NT * NPB;
        const size_t glds = (size_t)CH * 4 + (size_t)(3 * nbins + 1 + 3) * 4;
        bucket_gather_kernel<<<NB, 256, glds, stream>>>(
            x, offsets, packed, out, N, shift, NT);
    } else {
        hipMemsetAsync(d_out, 0, (size_t)out_size * sizeof(float), stream);
        scatter_add_kernel<<<8192, 256, 0, stream>>>(x, up_idx, down_idx, out, flag, E);
    }
}

// Round 7
// 460.920 us; speedup vs baseline: 2.4077x; 1.1464x over previous
//
#include <hip/hip_runtime.h>

// ChainMessagePassing: out[n] = sum over edges with dst==n of x[src], over two edge lists.
// x: [N=100000, 64] fp32; indices: [2, E=3200000] (src row 0, dst row 1), int64 or int32.
//
// R10: R9's tile-swept pipeline (gather FETCH 686->136MB, verified) with latency
// fixes on both remaining costs (gather 207us latency-bound at 37% occ / MLP~4;
// prep ~320us dominated by scatter's two global index passes at 3 blocks/CU):
//  - gather: tile-major key means a group's 4 nodes are ADJACENT bins -> one
//    contiguous sorted[] run per (tile,group); walk it 8-deep with 3-boundary
//    predication into 4 named accs (MLP 8). Register-stage packed between the
//    hist and scatter sort passes (single nt-read, -25.6MB). cursor merged into
//    cnt (LDS 26.4->22.7KB).
//  - scatter: single global read pass; (packed,bucket) register-staged
//    (CHUNK 4096 = 16/thread); 1563 blocks = 6.1/CU (was 3).

static constexpr int D = 64;
static constexpr int Q = 16;          // float4 quads per row
static constexpr int NPB = 64;        // nodes per bucket
static constexpr int NPB_SHIFT = 6;
static constexpr int CHUNK = 4096;    // edges per scatter block (16/thread)
static constexpr int CH = 4096;       // edges per gather sort chunk (16 KB LDS)
static constexpr int MAXT = 32;       // max src tiles (nbins <= 2048)

// ---- index dtype sniffer: int64 nonneg <2^31 has all-zero odd dwords ----
__global__ void detect_idx_dtype(const int* __restrict__ w, int* __restrict__ flag) {
    int tid = threadIdx.x;  // one wave
    int v = w[2 * tid + 1];
    unsigned long long m = __ballot(v != 0);
    if (tid == 0) *flag = (m == 0ULL) ? 1 : 0;
}

__device__ __forceinline__ int load_idx_nt(const void* idx, long long i, int is64) {
    return is64 ? (int)__builtin_nontemporal_load(((const long long*)idx) + i)
                : __builtin_nontemporal_load(((const int*)idx) + i);
}

// ---- phase 1: bucket histogram, LDS-aggregated ----
__global__ __launch_bounds__(256) void bucket_hist_kernel(
        const void* __restrict__ up, const void* __restrict__ down,
        int* __restrict__ bcounts, const int* __restrict__ flag, int E, int NB) {
    extern __shared__ int lcnt[];
    const int is64 = *flag;
    for (int i = threadIdx.x; i < NB; i += blockDim.x) lcnt[i] = 0;
    __syncthreads();
    const long long total = 2LL * E;
    const long long stride = (long long)gridDim.x * blockDim.x;
    for (long long e = (long long)blockIdx.x * blockDim.x + threadIdx.x;
         e < total; e += stride) {
        const void* idx = up; long long ee = e;
        if (ee >= E) { idx = down; ee -= E; }
        int dst = load_idx_nt(idx, E + ee, is64);
        atomicAdd(&lcnt[dst >> NPB_SHIFT], 1);
    }
    __syncthreads();
    for (int i = threadIdx.x; i < NB; i += blockDim.x)
        if (lcnt[i]) atomicAdd(&bcounts[i], lcnt[i]);
}

// ---- phase 2: exclusive scan over NB buckets, one block ----
__global__ __launch_bounds__(1024) void scan_kernel(
        const int* __restrict__ counts, int* __restrict__ offsets,
        int* __restrict__ cursors, int NB) {
    __shared__ int sums[1024];
    const int tid = threadIdx.x;
    const int chunk = (NB + 1023) / 1024;
    const int start = tid * chunk;
    const int end = min(start + chunk, NB);
    int s = 0;
    for (int i = start; i < end; i++) s += counts[i];
    sums[tid] = s;
    __syncthreads();
    for (int off = 1; off < 1024; off <<= 1) {
        int t = (tid >= off) ? sums[tid - off] : 0;
        __syncthreads();
        sums[tid] += t;
        __syncthreads();
    }
    int run = (tid == 0) ? 0 : sums[tid - 1];
    for (int i = start; i < end; i++) {
        offsets[i] = run;
        cursors[i] = run;
        run += counts[i];
    }
    if (tid == 1023) offsets[NB] = run;
}

// ---- phase 3: scatter packed (src<<6 | dst&63) into bucket bins ----
// SINGLE global read pass: (packed,bucket) register-staged (16/thread), LDS
// histogram -> one global atomicAdd per (block,bucket) reserves a contiguous
// sub-run -> LDS-cursored writes.
__global__ __launch_bounds__(256) void bucket_scatter_kernel(
        const void* __restrict__ up, const void* __restrict__ down,
        int* __restrict__ gcursor, unsigned* __restrict__ packed,
        const int* __restrict__ flag, int E, int NB) {
    extern __shared__ int lds[];
    int* cnt = lds;        // [NB]
    int* base = lds + NB;  // [NB]
    const int is64 = *flag;
    const long long total = 2LL * E;
    const long long cs = (long long)blockIdx.x * CHUNK;
    if (cs >= total) return;
    const int m = (int)(min(total, cs + (long long)CHUNK) - cs);
    const int tid = threadIdx.x;

    for (int i = tid; i < NB; i += 256) cnt[i] = 0;
    __syncthreads();

    unsigned pr[16];
    int bkt[16];
    #pragma unroll
    for (int k = 0; k < 16; k++) {
        const int i = tid + (k << 8);
        bkt[k] = -1;
        if (i < m) {
            long long e = cs + i;
            const void* idx = up; long long ee = e;
            if (ee >= E) { idx = down; ee -= E; }
            const int src = load_idx_nt(idx, ee, is64);
            const int dst = load_idx_nt(idx, E + ee, is64);
            pr[k] = ((unsigned)src << NPB_SHIFT) | (unsigned)(dst & (NPB - 1));
            bkt[k] = dst >> NPB_SHIFT;
            atomicAdd(&cnt[bkt[k]], 1);
        }
    }
    __syncthreads();
    for (int i = tid; i < NB; i += 256) {
        int c = cnt[i];
        base[i] = c ? atomicAdd(&gcursor[i], c) : 0;
        cnt[i] = 0;  // reuse as local cursor
    }
    __syncthreads();
    #pragma unroll
    for (int k = 0; k < 16; k++) {
        if (bkt[k] >= 0) {
            int pos = base[bkt[k]] + atomicAdd(&cnt[bkt[k]], 1);
            packed[pos] = pr[k];
        }
    }
}

// ---- phase 4: per-bucket counting sort by (src-tile, dstlo) + tile-swept
// register gather. Tile-major key => a group's 4 nodes are adjacent bins: one
// contiguous sorted[] run per (tile,group), walked 8-deep with 3-boundary
// predication into 4 named accumulators. packed register-staged between the
// sort's hist and scatter passes (single nt global read). ----
__global__ __launch_bounds__(256) void bucket_gather_kernel(
        const float* __restrict__ x, const int* __restrict__ offsets,
        const unsigned* __restrict__ packed, float* __restrict__ out,
        int N, int shift, int NT) {
    extern __shared__ int lds[];
    unsigned* sorted = (unsigned*)lds;        // [CH]
    int* cnt = lds + CH;                      // [nbins] -> becomes cursor
    int* binoff = cnt + NT * NPB;             // [nbins+1]
    const int nbins = NT * NPB;

    const int b = blockIdx.x;
    const int tid = threadIdx.x;
    const int g = tid >> 4;   // group 0..15 (owns nodes 4g..4g+3)
    const int q = tid & 15;   // quad within row
    const int beg = offsets[b], end = offsets[b + 1];
    const float* xq = x + q * 4;

    float4 acc0 = make_float4(0.f, 0.f, 0.f, 0.f);
    float4 acc1 = acc0, acc2 = acc0, acc3 = acc0;

#define ADDP(v, p) do {                                                        \
        const bool c1 = (p) < b1, c2 = (p) < b2, c3 = (p) < b3;                \
        acc0.x += c1 ? (v).x : 0.f; acc0.y += c1 ? (v).y : 0.f;                \
        acc0.z += c1 ? (v).z : 0.f; acc0.w += c1 ? (v).w : 0.f;                \
        const bool d1 = !c1 && c2;                                             \
        acc1.x += d1 ? (v).x : 0.f; acc1.y += d1 ? (v).y : 0.f;                \
        acc1.z += d1 ? (v).z : 0.f; acc1.w += d1 ? (v).w : 0.f;                \
        const bool d2 = !c2 && c3;                                             \
        acc2.x += d2 ? (v).x : 0.f; acc2.y += d2 ? (v).y : 0.f;                \
        acc2.z += d2 ? (v).z : 0.f; acc2.w += d2 ? (v).w : 0.f;                \
        const bool d3 = !c3;                                                   \
        acc3.x += d3 ? (v).x : 0.f; acc3.y += d3 ? (v).y : 0.f;                \
        acc3.z += d3 ? (v).z : 0.f; acc3.w += d3 ? (v).w : 0.f;                \
    } while (0)

    for (int cs = beg; cs < end; cs += CH) {
        const int m = min(CH, end - cs);
        for (int i = tid; i < nbins; i += 256) cnt[i] = 0;
        __syncthreads();
        // hist + register stage (CH == 16*256)
        unsigned pr[16];
        #pragma unroll
        for (int k = 0; k < 16; k++) {
            const int i = tid + (k << 8);
            if (i < m) {
                unsigned p = __builtin_nontemporal_load(packed + cs + i);
                pr[k] = p;
                int key = (int)((p >> (NPB_SHIFT + shift)) << NPB_SHIFT) | (int)(p & (NPB - 1));
                atomicAdd(&cnt[key], 1);
            }
        }
        __syncthreads();
        if (tid < 64) {  // wave 0: scan over nbins; cnt becomes exclusive cursor
            const int K = (nbins + 63) >> 6;
            const int base = tid * K;
            int S = 0;
            for (int k = 0; k < K; k++) {
                int i = base + k;
                if (i < nbins) S += cnt[i];
            }
            int inc = S;
            #pragma unroll
            for (int off = 1; off < 64; off <<= 1) {
                int t = __shfl_up(inc, off, 64);
                if (tid >= off) inc += t;
            }
            int run = inc - S;  // exclusive lane offset
            for (int k = 0; k < K; k++) {
                int i = base + k;
                if (i < nbins) {
                    int c = cnt[i];
                    cnt[i] = run;
                    binoff[i + 1] = run + c;
                    run += c;
                }
            }
            if (tid == 0) binoff[0] = 0;
        }
        __syncthreads();
        #pragma unroll
        for (int k = 0; k < 16; k++) {
            const int i = tid + (k << 8);
            if (i < m) {
                unsigned p = pr[k];
                int key = (int)((p >> (NPB_SHIFT + shift)) << NPB_SHIFT) | (int)(p & (NPB - 1));
                int pos = atomicAdd(&cnt[key], 1);
                sorted[pos] = p;
            }
        }
        __syncthreads();
        // tile-swept accumulation: contiguous run of the group's 4 nodes per tile
        for (int t = 0; t < NT; t++) {
            const int kb = t * NPB + 4 * g;
            const int b0 = binoff[kb];
            const int b1 = binoff[kb + 1];
            const int b2 = binoff[kb + 2];
            const int b3 = binoff[kb + 3];
            const int b4 = binoff[kb + 4];
            int e = b0;
            for (; e + 8 <= b4; e += 8) {  // 8 row-gathers in flight
                const unsigned p0 = sorted[e + 0], p1 = sorted[e + 1];
                const unsigned p2 = sorted[e + 2], p3 = sorted[e + 3];
                const unsigned p4 = sorted[e + 4], p5 = sorted[e + 5];
                const unsigned p6 = sorted[e + 6], p7 = sorted[e + 7];
                const float4 v0 = *(const float4*)(xq + ((long long)(p0 >> NPB_SHIFT)) * D);
                const float4 v1 = *(const float4*)(xq + ((long long)(p1 >> NPB_SHIFT)) * D);
                const float4 v2 = *(const float4*)(xq + ((long long)(p2 >> NPB_SHIFT)) * D);
                const float4 v3 = *(const float4*)(xq + ((long long)(p3 >> NPB_SHIFT)) * D);
                const float4 v4 = *(const float4*)(xq + ((long long)(p4 >> NPB_SHIFT)) * D);
                const float4 v5 = *(const float4*)(xq + ((long long)(p5 >> NPB_SHIFT)) * D);
                const float4 v6 = *(const float4*)(xq + ((long long)(p6 >> NPB_SHIFT)) * D);
                const float4 v7 = *(const float4*)(xq + ((long long)(p7 >> NPB_SHIFT)) * D);
                ADDP(v0, e + 0); ADDP(v1, e + 1); ADDP(v2, e + 2); ADDP(v3, e + 3);
                ADDP(v4, e + 4); ADDP(v5, e + 5); ADDP(v6, e + 6); ADDP(v7, e + 7);
            }
            for (; e < b4; e++) {
                const unsigned p = sorted[e];
                const float4 v = *(const float4*)(xq + ((long long)(p >> NPB_SHIFT)) * D);
                ADDP(v, e);
            }
        }
        __syncthreads();  // gather reads done before next chunk reuses LDS
    }
#undef ADDP

    const int node0 = b * NPB + 4 * g;
    if (node0 < N)
        *(float4*)(out + (long long)node0 * D + q * 4) = acc0;
    if (node0 + 1 < N)
        *(float4*)(out + (long long)(node0 + 1) * D + q * 4) = acc1;
    if (node0 + 2 < N)
        *(float4*)(out + (long long)(node0 + 2) * D + q * 4) = acc2;
    if (node0 + 3 < N)
        *(float4*)(out + (long long)(node0 + 3) * D + q * 4) = acc3;
}

// ---- fallback: direct fp32 atomics (R1), needs no workspace ----
__global__ __launch_bounds__(256) void scatter_add_kernel(
        const float* __restrict__ x, const void* __restrict__ up_idx,
        const void* __restrict__ down_idx, float* __restrict__ out,
        const int* __restrict__ dtype_flag, int num_edges) {
    const int is64 = *dtype_flag;
    const long long total = 2LL * num_edges * Q;
    const long long stride = (long long)gridDim.x * blockDim.x;
    for (long long t = (long long)blockIdx.x * blockDim.x + threadIdx.x;
         t < total; t += stride) {
        const int quad = (int)(t & (Q - 1));
        long long eg = t >> 4;
        const void* idx = up_idx;
        if (eg >= num_edges) { idx = down_idx; eg -= num_edges; }
        int src = load_idx_nt(idx, eg, is64);
        int dst = load_idx_nt(idx, num_edges + eg, is64);
        const float4 v = *(const float4*)(x + (long long)src * D + quad * 4);
        float* o = out + (long long)dst * D + quad * 4;
        unsafeAtomicAdd(o + 0, v.x);
        unsafeAtomicAdd(o + 1, v.y);
        unsafeAtomicAdd(o + 2, v.z);
        unsafeAtomicAdd(o + 3, v.w);
    }
}

extern "C" void kernel_launch(void* const* d_in, const int* in_sizes, int n_in,
                              void* d_out, int out_size, void* d_ws, size_t ws_size,
                              hipStream_t stream) {
    const float* x = (const float*)d_in[0];
    const void* up_idx = d_in[1];
    const void* down_idx = d_in[2];
    float* out = (float*)d_out;

    const int E = in_sizes[1] / 2;   // [2, E]
    const int N = out_size / D;      // [N, 64]
    const int NB = (N + NPB - 1) / NPB;
    const long long Etot = 2LL * E;

    // src tile shift: 8192 rows (2MB) preferred; coarsen so NT <= MAXT
    int shift = 13;
    while ((((long long)(N - 1) >> shift) + 1) > MAXT) shift++;
    const int NT = (int)(((long long)(N - 1) >> shift) + 1);

    // ws layout (ints): flag(64) | counts[NB] | offsets[NB+1] pad | cursors[NB] | packed[2E]
    int* ws_i = (int*)d_ws;
    int* flag = ws_i;
    int* counts = ws_i + 64;
    int* offsets = counts + NB;
    int* cursors = offsets + NB + 15;
    unsigned* packed = (unsigned*)(cursors + NB);
    const size_t ws_need = (size_t)(64 + 3LL * NB + 16 + Etot) * 4 + 64;

    detect_idx_dtype<<<1, 64, 0, stream>>>((const int*)up_idx, flag);

    if (ws_size >= ws_need && N <= (1 << 25) && Etot < (1LL << 31)) {
        hipMemsetAsync(counts, 0, (size_t)NB * sizeof(int), stream);
        bucket_hist_kernel<<<1024, 256, NB * sizeof(int), stream>>>(
            up_idx, down_idx, counts, flag, E, NB);
        scan_kernel<<<1, 1024, 0, stream>>>(counts, offsets, cursors, NB);
        const int sblocks = (int)((Etot + CHUNK - 1) / CHUNK);
        bucket_scatter_kernel<<<sblocks, 256, 2 * NB * sizeof(int), stream>>>(
            up_idx, down_idx, cursors, packed, flag, E, NB);
        const int nbins = NT * NPB;
        const size_t glds = (size_t)(CH + 2 * nbins + 4) * 4;
        bucket_gather_kernel<<<NB, 256, glds, stream>>>(
            x, offsets, packed, out, N, shift, NT);
    } else {
        hipMemsetAsync(d_out, 0, (size_t)out_size * sizeof(float), stream);
        scatter_add_kernel<<<8192, 256, 0, stream>>>(x, up_idx, down_idx, out, flag, E);
    }
}